// Round 9
// baseline (127.788 us; speedup 1.0000x reference)
//
#include <hip/hip_runtime.h>
#include <math.h>

#define NQ     9
#define B_DIM  48
#define S_DIM  96
#define D_DIM  54
#define DENC   4
#define DVAR   8
#define NFLAT  (B_DIM * S_DIM)   // 4608

typedef float f32x2 __attribute__((ext_vector_type(2)));

// Lane-xor primitives — R5/R8 hardware-validated set.
template<int LM>
__device__ __forceinline__ float lx(float v, int lane) {
    int x = __float_as_int(v);
    if constexpr (LM == 1)       x = __builtin_amdgcn_update_dpp(x, x, 0xB1, 0xF, 0xF, true);  // quad[1,0,3,2]
    else if constexpr (LM == 2)  x = __builtin_amdgcn_update_dpp(x, x, 0x4E, 0xF, 0xF, true);  // quad[2,3,0,1]
    else if constexpr (LM == 4)  x = __builtin_amdgcn_ds_swizzle(x, 0x101F);                   // xor4
    else if constexpr (LM == 8)  x = __builtin_amdgcn_update_dpp(x, x, 0x128, 0xF, 0xF, true); // ROW_ROR:8
    else if constexpr (LM == 16) x = __builtin_amdgcn_ds_swizzle(x, 0x401F);                   // xor16
    else {
        auto r = __builtin_amdgcn_permlane32_swap(x, x, false, false);
        // ret[0] = [lo,lo], ret[1] = [hi,hi]; want [hi,lo]
        x = (lane & 32) ? r[0] : r[1];
    }
    return __int_as_float(x);
}

__device__ __forceinline__ float wave_sum(float v, int lane) {
    v += lx<32>(v, lane);
    v += lx<16>(v, lane);
    v += lx<8>(v, lane);
    v += lx<4>(v, lane);
    v += lx<2>(v, lane);
    v += lx<1>(v, lane);
    return v;
}

// State layout: amp index i (9 bits) -> lane = i>>3 (bits 8..3), reg r = i&7 (bits 2..0).
// Qubit j <-> state bit BJ = 8-j.

__device__ __forceinline__ float bperm(int addr, float v) {
    return __int_as_float(__builtin_amdgcn_ds_bpermute(addr, __float_as_int(v)));
}

// Reg-local + lane-xor32 tail of the CNOT ring (stages (3,2)(2,1)(1,0)(0,8)).
__device__ __forceinline__ void ring_tail(f32x2 st[8], int lane) {
    // (3,2): ctrl lane bit0 (b3), tgt reg bit2
    {
        const bool c0 = (lane & 1) != 0;
#pragma unroll
        for (int r = 0; r < 4; ++r) {
            f32x2 a = st[r], b = st[r + 4];
            st[r]     = c0 ? b : a;
            st[r + 4] = c0 ? a : b;
        }
    }
    // (2,1): regs with bit2: r <-> r^2 (rename)
    { f32x2 t = st[4]; st[4] = st[6]; st[6] = t; }
    { f32x2 t = st[5]; st[5] = st[7]; st[7] = t; }
    // (1,0): regs with bit1: r <-> r^1 (rename)
    { f32x2 t = st[2]; st[2] = st[3]; st[3] = t; }
    { f32x2 t = st[6]; st[6] = st[7]; st[7] = t; }
    // (0,8): odd regs: xor32
#pragma unroll
    for (int r = 1; r < 8; r += 2) {
        st[r].x = lx<32>(st[r].x, lane);
        st[r].y = lx<32>(st[r].y, lane);
    }
}

// CNOT ring, single state. Stages (8,7)..(4,3) = Gray-code lane permutation
// (dst lane L pulls src lane L^(L>>1)) via ds_bpermute — R8-validated.
__device__ __forceinline__ void ring(f32x2 st[8], int lane) {
    const int gray = (lane ^ (lane >> 1)) << 2;
#pragma unroll
    for (int r = 0; r < 8; ++r) {
        st[r].x = bperm(gray, st[r].x);
        st[r].y = bperm(gray, st[r].y);
    }
    ring_tail(st, lane);
}

// CNOT ring on three states: all 48 bpermutes issued back-to-back so one
// lgkmcnt window amortizes DS latency 3-way, then reg-local fixups.
__device__ __forceinline__ void ring3(f32x2 sq[8], f32x2 sk[8], f32x2 sv[8], int lane) {
    const int gray = (lane ^ (lane >> 1)) << 2;
#pragma unroll
    for (int r = 0; r < 8; ++r) {
        sq[r].x = bperm(gray, sq[r].x);  sq[r].y = bperm(gray, sq[r].y);
        sk[r].x = bperm(gray, sk[r].x);  sk[r].y = bperm(gray, sk[r].y);
        sv[r].x = bperm(gray, sv[r].x);  sv[r].y = bperm(gray, sv[r].y);
    }
    ring_tail(sq, lane);
    ring_tail(sk, lane);
    ring_tail(sv, lane);
}

template<int BJ>
__device__ __forceinline__ void rot_ry(f32x2 st[8], float c, float s, int lane) {
    const f32x2 c2 = {c, c};
    if constexpr (BJ >= 3) {
        constexpr int lm = 1 << (BJ - 3);
        const float sg = (lane & lm) ? s : -s;
        const f32x2 sg2 = {sg, sg};
#pragma unroll
        for (int r = 0; r < 8; ++r) {
            f32x2 p = { lx<lm>(st[r].x, lane), lx<lm>(st[r].y, lane) };
            st[r] = st[r] * c2 + p * sg2;
        }
    } else {
        constexpr int M = 1 << BJ;
        const f32x2 s2 = {s, s}, ns2 = {-s, -s};
#pragma unroll
        for (int r = 0; r < 8; ++r) {
            if ((r & M) == 0) {
                f32x2 a = st[r], b = st[r + M];
                st[r]     = a * c2 + b * ns2;
                st[r + M] = b * c2 + a * s2;
            }
        }
    }
}

template<int BJ>
__device__ __forceinline__ void rot_rx(f32x2 st[8], float c, float s, int lane) {
    if constexpr (BJ >= 3) {
        constexpr int lm = 1 << (BJ - 3);
#pragma unroll
        for (int r = 0; r < 8; ++r) {
            float px = lx<lm>(st[r].x, lane), py = lx<lm>(st[r].y, lane);
            float nx = fmaf(s, py, c * st[r].x);
            float ny = fmaf(-s, px, c * st[r].y);
            st[r].x = nx; st[r].y = ny;
        }
    } else {
        constexpr int M = 1 << BJ;
#pragma unroll
        for (int r = 0; r < 8; ++r) {
            if ((r & M) == 0) {
                f32x2 a = st[r], b = st[r + M];
                st[r].x     = fmaf(s, b.y, c * a.x);
                st[r].y     = fmaf(-s, b.x, c * a.y);
                st[r + M].x = fmaf(s, a.y, c * b.x);
                st[r + M].y = fmaf(-s, a.x, c * b.y);
            }
        }
    }
}

#define INITQ(j) { f32x2 c0 = cs[2 * (j)], c1 = cs[2 * (j) + 1];      \
                   rot_rx<8 - (j)>(st, c0.x, c0.y, lane);             \
                   rot_ry<8 - (j)>(st, c1.x, c1.y, lane); }

// Single-stream circuit (encoding phase).
__device__ __forceinline__ void run_circuit(f32x2 st[8], const f32x2* cs, int layers, int lane) {
    INITQ(0) INITQ(1) INITQ(2) INITQ(3) INITQ(4)
    INITQ(5) INITQ(6) INITQ(7) INITQ(8)
    const f32x2* p = cs + 18;
#pragma unroll 1
    for (int L = 0; L < layers; ++L) {
        ring(st, lane);
        { f32x2 cc = p[0]; rot_ry<8>(st, cc.x, cc.y, lane); }
        { f32x2 cc = p[1]; rot_ry<7>(st, cc.x, cc.y, lane); }
        { f32x2 cc = p[2]; rot_ry<6>(st, cc.x, cc.y, lane); }
        { f32x2 cc = p[3]; rot_ry<5>(st, cc.x, cc.y, lane); }
        { f32x2 cc = p[4]; rot_ry<4>(st, cc.x, cc.y, lane); }
        { f32x2 cc = p[5]; rot_ry<3>(st, cc.x, cc.y, lane); }
        { f32x2 cc = p[6]; rot_ry<2>(st, cc.x, cc.y, lane); }
        { f32x2 cc = p[7]; rot_ry<1>(st, cc.x, cc.y, lane); }
        { f32x2 cc = p[8]; rot_ry<0>(st, cc.x, cc.y, lane); }
        p += 9;
    }
}

// Three independent variational circuits (Q,K,V) interleaved for ILP.
__device__ __forceinline__ void run3(f32x2 sq[8], f32x2 sk[8], f32x2 sv[8],
                                     const f32x2* csq, const f32x2* csk, const f32x2* csv,
                                     int lane) {
#define INITQ3(j) { \
        f32x2 aq = csq[2*(j)],   ak = csk[2*(j)],   av = csv[2*(j)];   \
        rot_rx<8-(j)>(sq, aq.x, aq.y, lane);                           \
        rot_rx<8-(j)>(sk, ak.x, ak.y, lane);                           \
        rot_rx<8-(j)>(sv, av.x, av.y, lane);                           \
        f32x2 bq = csq[2*(j)+1], bk = csk[2*(j)+1], bv = csv[2*(j)+1]; \
        rot_ry<8-(j)>(sq, bq.x, bq.y, lane);                           \
        rot_ry<8-(j)>(sk, bk.x, bk.y, lane);                           \
        rot_ry<8-(j)>(sv, bv.x, bv.y, lane); }
    INITQ3(0) INITQ3(1) INITQ3(2) INITQ3(3) INITQ3(4)
    INITQ3(5) INITQ3(6) INITQ3(7) INITQ3(8)
#undef INITQ3
    const f32x2 *pq = csq + 18, *pk = csk + 18, *pv = csv + 18;
#pragma unroll 1
    for (int L = 0; L < DVAR; ++L) {
        ring3(sq, sk, sv, lane);
#define RY3(i, BJ) { f32x2 a = pq[i], b = pk[i], c = pv[i];            \
        rot_ry<BJ>(sq, a.x, a.y, lane);                                \
        rot_ry<BJ>(sk, b.x, b.y, lane);                                \
        rot_ry<BJ>(sv, c.x, c.y, lane); }
        RY3(0, 8) RY3(1, 7) RY3(2, 6) RY3(3, 5) RY3(4, 4)
        RY3(5, 3) RY3(6, 2) RY3(7, 1) RY3(8, 0)
#undef RY3
        pq += 9; pk += 9; pv += 9;
    }
}

// <Z>, <X>, <Y> on qubit with state-bit BJ.
template<int BJ>
__device__ __forceinline__ void expv(const f32x2 st[8], int lane, float& ez, float& ex, float& ey) {
    ez = ex = ey = 0.f;
    if constexpr (BJ >= 3) {
        constexpr int lm = 1 << (BJ - 3);
        const float sgn = (lane & lm) ? -1.f : 1.f;
#pragma unroll
        for (int r = 0; r < 8; ++r) {
            float px = lx<lm>(st[r].x, lane);
            float py = lx<lm>(st[r].y, lane);
            ez += sgn * (st[r].x * st[r].x + st[r].y * st[r].y);
            ex += st[r].x * px + st[r].y * py;
            ey += sgn * (st[r].x * py - st[r].y * px);
        }
    } else {
        constexpr int M = 1 << BJ;
#pragma unroll
        for (int r = 0; r < 8; ++r) {
            if ((r & M) == 0) {
                f32x2 a = st[r], b = st[r + M];
                ez += (a.x * a.x + a.y * a.y) - (b.x * b.x + b.y * b.y);
                ex += 2.f * (a.x * b.x + a.y * b.y);
                ey += 2.f * (a.x * b.y - a.y * b.x);
            }
        }
    }
    ez = wave_sum(ez, lane); ex = wave_sum(ex, lane); ey = wave_sum(ey, lane);
}

__global__ __launch_bounds__(64, 4) void sim_kernel(
    const float* __restrict__ inp, const float* __restrict__ wq,
    const float* __restrict__ wk,  const float* __restrict__ wv,
    float* __restrict__ outQ, float* __restrict__ outK, float* __restrict__ outV)
{
    __shared__ f32x2 cs[54 + 270];   // {cos(t/2), sin(t/2)} per angle

    const int lane = threadIdx.x;
    const int fi   = blockIdx.x;     // flat = s*B + b
    const int b = fi % B_DIM, s = fi / B_DIM;
    const float* x = inp + ((size_t)b * S_DIM + s) * D_DIM;

    for (int k = lane; k < 324; k += 64) {
        float ang = (k < 54)  ? x[k]
                  : (k < 144) ? wq[k - 54]
                  : (k < 234) ? wk[k - 144]
                              : wv[k - 234];
        float sn, cn; sincosf(0.5f * ang, &sn, &cn);
        f32x2 v = {cn, sn};
        cs[k] = v;
    }
    // single wave: LDS write->read ordering handled by lgkmcnt, no barrier needed

    f32x2 sq[8], sk[8], sv[8];
#pragma unroll
    for (int r = 0; r < 8; ++r) { f32x2 z = {0.f, 0.f}; sq[r] = z; }
    if (lane == 0) sq[0].x = 1.f;

    // Shared encoding circuit on sq, then fork.
    run_circuit(sq, cs, DENC, lane);
#pragma unroll
    for (int r = 0; r < 8; ++r) { sk[r] = sq[r]; sv[r] = sq[r]; }

    run3(sq, sk, sv, cs + 54, cs + 144, cs + 234, lane);

    // ---- Q: <Z_0> (qubit 0 = state bit 8 = lane bit 5) ----
    {
        float p = 0.f;
#pragma unroll
        for (int r = 0; r < 8; ++r) p += sq[r].x * sq[r].x + sq[r].y * sq[r].y;
        p = (lane & 32) ? -p : p;
        p = wave_sum(p, lane);
        if (lane == 0) outQ[fi] = p;
    }
    // ---- K ----
    {
        float p = 0.f;
#pragma unroll
        for (int r = 0; r < 8; ++r) p += sk[r].x * sk[r].x + sk[r].y * sk[r].y;
        p = (lane & 32) ? -p : p;
        p = wave_sum(p, lane);
        if (lane == 0) outK[fi] = p;
    }
    // ---- V ----
    {
        float* vrow = outV + (size_t)fi * D_DIM;
#define EXPQ(q) { float ez, ex, ey; expv<8 - (q)>(sv, lane, ez, ex, ey);            \
                  if (lane == 0) { vrow[(q)] = ez; vrow[9 + (q)] = ex;              \
                                   vrow[18 + (q)] = ey; vrow[27 + (q)] = ez;        \
                                   vrow[36 + (q)] = ex; vrow[45 + (q)] = ey; } }
        EXPQ(0) EXPQ(1) EXPQ(2) EXPQ(3) EXPQ(4)
        EXPQ(5) EXPQ(6) EXPQ(7) EXPQ(8)
#undef EXPQ
    }
}

__global__ __launch_bounds__(256) void attn_kernel(
    const float* __restrict__ inp, const float* __restrict__ Q,
    const float* __restrict__ K,   const float* __restrict__ V,
    float* __restrict__ out)
{
    __shared__ float w4[4][S_DIM];
    const int warp = threadIdx.x >> 6;
    const int t    = threadIdx.x & 63;
    const int bi   = blockIdx.x * 4 + warp;   // b*S + i
    const int b    = bi / S_DIM;
    const int i    = bi % S_DIM;
    float* w = w4[warp];

    const float q = Q[i * B_DIM + b];
    float e0, e1 = 0.f;
    {
        float d0 = q - K[t * B_DIM + b];
        e0 = expf(-d0 * d0);
        w[t] = e0;
        if (t < S_DIM - 64) {
            float d1 = q - K[(t + 64) * B_DIM + b];
            e1 = expf(-d1 * d1);
            w[t + 64] = e1;
        }
    }
    float ps = wave_sum(e0 + e1, t);
    const float inv = 1.f / ps;

    if (t < D_DIM) {
        float acc = 0.f;
        for (int j = 0; j < S_DIM; ++j)
            acc += w[j] * V[(size_t)(j * B_DIM + b) * D_DIM + t];
        size_t o = (size_t)bi * D_DIM + t;
        out[o] = inp[o] + acc * inv;
    }
}

extern "C" void kernel_launch(void* const* d_in, const int* in_sizes, int n_in,
                              void* d_out, int out_size, void* d_ws, size_t ws_size,
                              hipStream_t stream)
{
    (void)in_sizes; (void)n_in; (void)out_size; (void)ws_size;
    const float* inp = (const float*)d_in[0];
    const float* wq  = (const float*)d_in[1];
    const float* wk  = (const float*)d_in[2];
    const float* wv  = (const float*)d_in[3];
    float* outp = (float*)d_out;

    float* Qw = (float*)d_ws;
    float* Kw = Qw + NFLAT;
    float* Vw = Kw + NFLAT;

    sim_kernel<<<NFLAT, 64, 0, stream>>>(inp, wq, wk, wv, Qw, Kw, Vw);
    attn_kernel<<<NFLAT / 4, 256, 0, stream>>>(inp, Qw, Kw, Vw, outp);
}